// Round 5
// baseline (305.178 us; speedup 1.0000x reference)
//
#include <hip/hip_runtime.h>
#include <hip/hip_bf16.h>
#include <stdint.h>

// Problem constants (B=4, N=1024, F=1024, H=16, D=64)
#define FDIM 1024
#define NHEADS 16
#define HDIM 64
#define BATCH 4
#define SEQ 1024
#define MROWS (BATCH*SEQ)   // 4096

typedef short bf16x8 __attribute__((ext_vector_type(8)));
typedef float f32x4 __attribute__((ext_vector_type(4)));

__device__ inline unsigned short f2bf(float f){
  union { float f; uint32_t u; } v; v.f = f;
  uint32_t u = v.u;
  uint32_t r = (u + 0x7fffu + ((u >> 16) & 1u)) >> 16;
  return (unsigned short)r;
}

__device__ inline void gld_lds16(const void* g, void* l){
  __builtin_amdgcn_global_load_lds((const __attribute__((address_space(1))) uint32_t*)g,
                                   (__attribute__((address_space(3))) uint32_t*)l, 16, 0, 0);
}

// swizzled LDS b128 read: tile [64 rows][8 colgroups of 8 bf16], phys cg = cg ^ (row&7)
__device__ inline bf16x8 ldsw(const unsigned short* base, int row, int colgrp){
  return *(const bf16x8*)&base[row*64 + (((colgrp) ^ (row&7))<<3)];
}

// DPP rotate-right by N within each 16-lane row (VALU pipe, not DS)
template<int N>
__device__ inline float dppRor(float x){
  int r = __builtin_amdgcn_update_dpp(0, __float_as_int(x), 0x120|N, 0xF, 0xF, true);
  return __int_as_float(r);
}
__device__ inline float rowMax16(float x){
  x = fmaxf(x, dppRor<1>(x)); x = fmaxf(x, dppRor<2>(x));
  x = fmaxf(x, dppRor<4>(x)); x = fmaxf(x, dppRor<8>(x));
  return x;
}
__device__ inline float rowSum16(float x){
  x += dppRor<1>(x); x += dppRor<2>(x); x += dppRor<4>(x); x += dppRor<8>(x);
  return x;
}

// ---------------- all three weights fp32 -> bf16, one launch ----------------
__global__ __launch_bounds__(256) void cvt_all(const float* __restrict__ wqk,
                                               const float* __restrict__ wv,
                                               const float* __restrict__ wo,
                                               unsigned short* __restrict__ oqk,
                                               unsigned short* __restrict__ ov,
                                               unsigned short* __restrict__ oo){
  int i = blockIdx.x*256 + threadIdx.x;   // in float4 units; total 1048576
  const float* src; unsigned short* dst; int j;
  if (i < 524288)      { src = wqk; dst = oqk; j = i; }
  else if (i < 786432) { src = wv;  dst = ov;  j = i - 524288; }
  else                 { src = wo;  dst = oo;  j = i - 786432; }
  float4 v = ((const float4*)src)[j];
  ushort4 o; o.x=f2bf(v.x); o.y=f2bf(v.y); o.z=f2bf(v.z); o.w=f2bf(v.w);
  ((ushort4*)dst)[j] = o;
}

// ---------------- LayerNorm + pos add ----------------
__global__ __launch_bounds__(256) void ln_posadd(const float* __restrict__ x,
                                                 const float* __restrict__ pos,
                                                 const float* __restrict__ g,
                                                 const float* __restrict__ be,
                                                 unsigned short* __restrict__ normb,
                                                 unsigned short* __restrict__ posnb){
  int row = blockIdx.x, t = threadIdx.x;
  float4 v = ((const float4*)(x + (size_t)row*FDIM))[t];
  float s  = v.x+v.y+v.z+v.w;
  float sq = v.x*v.x+v.y*v.y+v.z*v.z+v.w*v.w;
  #pragma unroll
  for (int off=32; off>=1; off>>=1){ s += __shfl_down(s,off); sq += __shfl_down(sq,off); }
  __shared__ float red[8];
  int w=t>>6, lane=t&63;
  if (!lane){ red[w]=s; red[4+w]=sq; }
  __syncthreads();
  s  = red[0]+red[1]+red[2]+red[3];
  sq = red[4]+red[5]+red[6]+red[7];
  float mu  = s*(1.0f/FDIM);
  float var = sq*(1.0f/FDIM) - mu*mu;
  float rs  = rsqrtf(var + 1e-5f);
  float4 gg=((const float4*)g)[t], bb=((const float4*)be)[t];
  float4 pp=((const float4*)(pos + (size_t)row*FDIM))[t];
  float n0=(v.x-mu)*rs*gg.x+bb.x, n1=(v.y-mu)*rs*gg.y+bb.y;
  float n2=(v.z-mu)*rs*gg.z+bb.z, n3=(v.w-mu)*rs*gg.w+bb.w;
  ushort4 nb; nb.x=f2bf(n0); nb.y=f2bf(n1); nb.z=f2bf(n2); nb.w=f2bf(n3);
  ushort4 pb; pb.x=f2bf(n0+pp.x); pb.y=f2bf(n1+pp.y); pb.z=f2bf(n2+pp.z); pb.w=f2bf(n3+pp.w);
  ((ushort4*)(normb+(size_t)row*FDIM))[t]=nb;
  ((ushort4*)(posnb+(size_t)row*FDIM))[t]=pb;
}

// ---------------- GEMM: C[M,N] = A[M,K] @ W[N,K]^T + bias ----------------
// MODE 0: bf16 store, bias[n]. MODE 1: fp32 store + bias[n] + resid.
// MODE 2: bf16 store, bias[m] (V^T = Wv @ norm^T).
// MODE 3: bf16 store, bias[n], then scale by QSCL when n < FDIM (pre-scaled Q).
#define QSCL 0.1803368801111204f   // 0.125 * log2(e)
template<int MODE>
__global__ __launch_bounds__(256) void gemm_bt(const unsigned short* __restrict__ A,
                                               const unsigned short* __restrict__ Bw,
                                               const float* __restrict__ bias,
                                               const float* __restrict__ resid,
                                               void* __restrict__ Cout,
                                               int M, int Nout, int K){
  __shared__ unsigned short Als[128*32];
  __shared__ unsigned short Bls[128*32];
  int t = threadIdx.x, w = t>>6, lane = t&63;
  int m0 = blockIdx.x*128, n0 = blockIdx.y*128;
  int wm = (w>>1)*64, wn = (w&1)*64;
  int lrow = lane&15, lk = (lane>>4)*8, rg = lane>>4;
  f32x4 acc[4][4] = {};
  for (int k0=0; k0<K; k0+=32){
    #pragma unroll
    for (int i=0;i<2;i++){
      int c = t + i*256;
      gld_lds16(A  + (size_t)(m0 + (c>>2))*K + k0 + (c&3)*8, Als + c*8);
      gld_lds16(Bw + (size_t)(n0 + (c>>2))*K + k0 + (c&3)*8, Bls + c*8);
    }
    __syncthreads();
    bf16x8 a[4], b[4];
    #pragma unroll
    for (int i=0;i<4;i++){
      a[i] = *(const bf16x8*)&Als[(wm + i*16 + lrow)*32 + lk];
      b[i] = *(const bf16x8*)&Bls[(wn + i*16 + lrow)*32 + lk];
    }
    #pragma unroll
    for (int mi=0;mi<4;mi++)
      #pragma unroll
      for (int ni=0;ni<4;ni++)
        acc[mi][ni] = __builtin_amdgcn_mfma_f32_16x16x32_bf16(a[mi], b[ni], acc[mi][ni], 0,0,0);
    __syncthreads();
  }
  #pragma unroll
  for (int mi=0;mi<4;mi++){
    #pragma unroll
    for (int ni=0;ni<4;ni++){
      int n = n0 + wn + ni*16 + lrow;
      float bs = (MODE==2) ? 0.f : bias[n];
      float scl = (MODE==3 && n < FDIM) ? QSCL : 1.0f;
      #pragma unroll
      for (int r=0;r<4;r++){
        int m = m0 + wm + mi*16 + rg*4 + r;
        float vv = acc[mi][ni][r] + ((MODE==2) ? bias[m] : bs);
        if (MODE==3) vv *= scl;
        size_t idx = (size_t)m*Nout + n;
        if (MODE==1) ((float*)Cout)[idx] = vv + resid[idx];
        else         ((unsigned short*)Cout)[idx] = f2bf(vv);
      }
    }
  }
}

// ---------------- Flash attention: no staging, no barriers ----------------
// K/V/Q read directly from global (L2-hot: 256 KB per (b,h), XCD-chunked).
// Q is pre-scaled by 0.125*log2(e) in the QK-gemm epilogue -> softmax uses exp2 directly.
// Only LDS: P tile [64 q][64 key] (XOR-swizzled), same-wave produce/consume.
// qk: [B*N, 2F] bf16; vt: [F][B*N] bf16 (V^T, key-contiguous rows).
__global__ __launch_bounds__(256, 4) void attn(const unsigned short* __restrict__ qk,
                                               const unsigned short* __restrict__ vt,
                                               unsigned short* __restrict__ wvbuf){
  __shared__ unsigned short Pls[64*64];
  int t=threadIdx.x, w=t>>6, lane=t&63;
  int lrow=lane&15, lcg=lane>>4, rg=lane>>4;
  // XCD-chunked decode: 128 consecutive logical wgids (same b,h group) per XCD
  int bid = blockIdx.x;
  int wgid = (bid&7)*128 + (bid>>3);
  int q0 = (wgid&15)*64, h = (wgid>>4)&15, b = wgid>>8;
  const size_t qs = 2*FDIM;

  // Q fragments: row q0 + w*16 + lrow, d-slices lcg*8 and 32+lcg*8
  const unsigned short* qrow = qk + (size_t)(b*SEQ + q0 + w*16 + lrow)*qs + h*HDIM;
  bf16x8 qa0 = *(const bf16x8*)(qrow + lcg*8);
  bf16x8 qa1 = *(const bf16x8*)(qrow + 32 + lcg*8);

  // K: row (b*SEQ + key), col F + h*64 + d;  lane reads row key0+ni*16+lrow, d-slice kf*32+lcg*8
  const unsigned short* kbase = qk + (size_t)(b*SEQ + lrow)*qs + FDIM + h*HDIM + lcg*8;
  // V^T: row (h*64 + d), col (b*SEQ + key); lane reads row nd*16+lrow, key-slice kf*32+lcg*8
  const unsigned short* vbase = vt + (size_t)(h*HDIM + lrow)*MROWS + b*SEQ + lcg*8;

  f32x4 o[4] = {};
  float m_run[4], l_run[4];
  #pragma unroll
  for (int r=0;r<4;r++){ m_run[r]=-1e30f; l_run[r]=0.f; }

  for (int kt=0; kt<16; ++kt){
    // S = Q K^T (16 q-rows x 64 keys per wave); Q pre-scaled -> S already in exp2 domain
    f32x4 s[4] = {};
    #pragma unroll
    for (int ni=0;ni<4;ni++){
      bf16x8 kb0 = *(const bf16x8*)(kbase + (size_t)(kt*64 + ni*16)*qs);
      bf16x8 kb1 = *(const bf16x8*)(kbase + (size_t)(kt*64 + ni*16)*qs + 32);
      s[ni] = __builtin_amdgcn_mfma_f32_16x16x32_bf16(qa0, kb0, s[ni], 0,0,0);
      s[ni] = __builtin_amdgcn_mfma_f32_16x16x32_bf16(qa1, kb1, s[ni], 0,0,0);
    }
    // online softmax (exp2 domain); q_local = rg*4+r, key = ni*16 + lrow
    #pragma unroll
    for (int r=0;r<4;r++){
      float tm = fmaxf(fmaxf(s[0][r],s[1][r]), fmaxf(s[2][r],s[3][r]));
      tm = rowMax16(tm);
      float mn = fmaxf(m_run[r], tm);
      float sc = exp2f(m_run[r] - mn);
      float p[4]; float ts = 0.f;
      #pragma unroll
      for (int ni=0;ni<4;ni++){ p[ni] = exp2f(s[ni][r] - mn); ts += p[ni]; }
      ts = rowSum16(ts);
      l_run[r] = l_run[r]*sc + ts;
      m_run[r] = mn;
      #pragma unroll
      for (int nd=0;nd<4;nd++) o[nd][r] *= sc;
      int pr = w*16 + rg*4 + r;
      #pragma unroll
      for (int ni=0;ni<4;ni++)
        Pls[pr*64 + (((ni*2 + (lrow>>3)) ^ (pr&7))<<3) + (lrow&7)] = f2bf(p[ni]);
    }
    // O += P V  (P rows produced and consumed by the same wave; DS pipe is in-order)
    #pragma unroll
    for (int kf=0; kf<2; kf++){
      bf16x8 pa = ldsw(Pls, w*16+lrow, kf*4 + lcg);
      #pragma unroll
      for (int nd=0;nd<4;nd++){
        bf16x8 vb = *(const bf16x8*)(vbase + (size_t)(nd*16)*MROWS + kt*64 + kf*32);
        o[nd] = __builtin_amdgcn_mfma_f32_16x16x32_bf16(pa, vb, o[nd], 0,0,0);
      }
    }
  }
  // epilogue: divide by softmax denom, store bf16
  #pragma unroll
  for (int nd=0; nd<4; nd++){
    #pragma unroll
    for (int r=0;r<4;r++){
      float val = o[nd][r] / l_run[r];
      wvbuf[(size_t)(b*SEQ + q0 + w*16 + rg*4 + r)*FDIM + h*HDIM + nd*16 + lrow] = f2bf(val);
    }
  }
}

extern "C" void kernel_launch(void* const* d_in, const int* in_sizes, int n_in,
                              void* d_out, int out_size, void* d_ws, size_t ws_size,
                              hipStream_t stream) {
  const float* in_feats = (const float*)d_in[0];
  const float* pos      = (const float*)d_in[1];
  const float* ln_g     = (const float*)d_in[2];
  const float* ln_b     = (const float*)d_in[3];
  const float* w_qk     = (const float*)d_in[4];
  const float* b_qk     = (const float*)d_in[5];
  const float* w_v      = (const float*)d_in[6];
  const float* b_v      = (const float*)d_in[7];
  const float* w_o      = (const float*)d_in[8];
  const float* b_o      = (const float*)d_in[9];
  float* out = (float*)d_out;

  char* ws = (char*)d_ws;
  unsigned short* norm_b = (unsigned short*)(ws + 0);              // 8 MiB
  unsigned short* posn_b = (unsigned short*)(ws + (8u<<20));       // 8 MiB
  unsigned short* wqk_b  = (unsigned short*)(ws + (16u<<20));      // 4 MiB
  unsigned short* wv_b   = (unsigned short*)(ws + (20u<<20));      // 2 MiB
  unsigned short* wo_b   = (unsigned short*)(ws + (22u<<20));      // 2 MiB
  unsigned short* qk_buf = (unsigned short*)(ws + (24u<<20));      // 16 MiB
  unsigned short* vt_buf = (unsigned short*)(ws + (40u<<20));      // 8 MiB  [1024][4096]
  unsigned short* wv_out = norm_b;  // reuse: norm no longer needed once attn runs

  cvt_all<<<4096, 256, 0, stream>>>(w_qk, w_v, w_o, wqk_b, wv_b, wo_b);
  ln_posadd<<<MROWS, 256, 0, stream>>>(in_feats, pos, ln_g, ln_b, norm_b, posn_b);
  // QK projection: [4096,2048] = posn @ w_qk^T ; Q half pre-scaled by 0.125*log2(e)
  gemm_bt<3><<<dim3(MROWS/128, 2048/128), 256, 0, stream>>>(posn_b, wqk_b, b_qk, nullptr,
                                                            qk_buf, MROWS, 2048, FDIM);
  // V^T projection: [1024,4096] = w_v @ norm^T  (bias per output row)
  gemm_bt<2><<<dim3(FDIM/128, MROWS/128), 256, 0, stream>>>(wv_b, norm_b, b_v, nullptr,
                                                            vt_buf, FDIM, MROWS, FDIM);
  attn<<<dim3(SEQ/64 * NHEADS * BATCH), 256, 0, stream>>>(qk_buf, vt_buf, wv_out);
  // O projection + bias + residual -> fp32 out
  gemm_bt<1><<<dim3(MROWS/128, 1024/128), 256, 0, stream>>>(wv_out, wo_b, b_o, in_feats,
                                                            out, MROWS, 1024, FDIM);
}

// Round 8
// 250.935 us; speedup vs baseline: 1.2162x; 1.2162x over previous
//
#include <hip/hip_runtime.h>
#include <hip/hip_bf16.h>
#include <stdint.h>

// Problem constants (B=4, N=1024, F=1024, H=16, D=64)
#define FDIM 1024
#define NHEADS 16
#define HDIM 64
#define BATCH 4
#define SEQ 1024
#define MROWS (BATCH*SEQ)   // 4096

typedef short bf16x8 __attribute__((ext_vector_type(8)));
typedef float f32x4 __attribute__((ext_vector_type(4)));
typedef float f32x16 __attribute__((ext_vector_type(16)));

__device__ inline unsigned short f2bf(float f){
  union { float f; uint32_t u; } v; v.f = f;
  uint32_t u = v.u;
  uint32_t r = (u + 0x7fffu + ((u >> 16) & 1u)) >> 16;
  return (unsigned short)r;
}

__device__ inline uint32_t cvtpk(float lo, float hi){
  uint32_t r;
  asm("v_cvt_pk_bf16_f32 %0, %1, %2" : "=v"(r) : "v"(lo), "v"(hi));
  return r;
}

__device__ inline void gld_lds16(const void* g, void* l){
  __builtin_amdgcn_global_load_lds((const __attribute__((address_space(1))) uint32_t*)g,
                                   (__attribute__((address_space(3))) uint32_t*)l, 16, 0, 0);
}

// ---------------- all three weights fp32 -> bf16, one launch ----------------
__global__ __launch_bounds__(256) void cvt_all(const float* __restrict__ wqk,
                                               const float* __restrict__ wv,
                                               const float* __restrict__ wo,
                                               unsigned short* __restrict__ oqk,
                                               unsigned short* __restrict__ ov,
                                               unsigned short* __restrict__ oo){
  int i = blockIdx.x*256 + threadIdx.x;   // in float4 units; total 1048576
  const float* src; unsigned short* dst; int j;
  if (i < 524288)      { src = wqk; dst = oqk; j = i; }
  else if (i < 786432) { src = wv;  dst = ov;  j = i - 524288; }
  else                 { src = wo;  dst = oo;  j = i - 786432; }
  float4 v = ((const float4*)src)[j];
  ushort4 o; o.x=f2bf(v.x); o.y=f2bf(v.y); o.z=f2bf(v.z); o.w=f2bf(v.w);
  ((ushort4*)dst)[j] = o;
}

// ---------------- LayerNorm + pos add ----------------
__global__ __launch_bounds__(256) void ln_posadd(const float* __restrict__ x,
                                                 const float* __restrict__ pos,
                                                 const float* __restrict__ g,
                                                 const float* __restrict__ be,
                                                 unsigned short* __restrict__ normb,
                                                 unsigned short* __restrict__ posnb){
  int row = blockIdx.x, t = threadIdx.x;
  float4 v = ((const float4*)(x + (size_t)row*FDIM))[t];
  float s  = v.x+v.y+v.z+v.w;
  float sq = v.x*v.x+v.y*v.y+v.z*v.z+v.w*v.w;
  #pragma unroll
  for (int off=32; off>=1; off>>=1){ s += __shfl_down(s,off); sq += __shfl_down(sq,off); }
  __shared__ float red[8];
  int w=t>>6, lane=t&63;
  if (!lane){ red[w]=s; red[4+w]=sq; }
  __syncthreads();
  s  = red[0]+red[1]+red[2]+red[3];
  sq = red[4]+red[5]+red[6]+red[7];
  float mu  = s*(1.0f/FDIM);
  float var = sq*(1.0f/FDIM) - mu*mu;
  float rs  = rsqrtf(var + 1e-5f);
  float4 gg=((const float4*)g)[t], bb=((const float4*)be)[t];
  float4 pp=((const float4*)(pos + (size_t)row*FDIM))[t];
  float n0=(v.x-mu)*rs*gg.x+bb.x, n1=(v.y-mu)*rs*gg.y+bb.y;
  float n2=(v.z-mu)*rs*gg.z+bb.z, n3=(v.w-mu)*rs*gg.w+bb.w;
  ushort4 nb; nb.x=f2bf(n0); nb.y=f2bf(n1); nb.z=f2bf(n2); nb.w=f2bf(n3);
  ushort4 pb; pb.x=f2bf(n0+pp.x); pb.y=f2bf(n1+pp.y); pb.z=f2bf(n2+pp.z); pb.w=f2bf(n3+pp.w);
  ((ushort4*)(normb+(size_t)row*FDIM))[t]=nb;
  ((ushort4*)(posnb+(size_t)row*FDIM))[t]=pb;
}

// ---------------- GEMM: C[M,N] = A[M,K] @ W[N,K]^T + bias ----------------
// MODE 0: bf16 store, bias[n]. MODE 1: fp32 store + bias[n] + resid.
// MODE 2: bf16 store, bias[m] (V^T = Wv @ norm^T).
// MODE 3: bf16 store, bias[n], then scale by QSCL when n < FDIM (pre-scaled Q).
#define QSCL 0.1803368801111204f   // 0.125 * log2(e)
template<int MODE>
__global__ __launch_bounds__(256) void gemm_bt(const unsigned short* __restrict__ A,
                                               const unsigned short* __restrict__ Bw,
                                               const float* __restrict__ bias,
                                               const float* __restrict__ resid,
                                               void* __restrict__ Cout,
                                               int M, int Nout, int K){
  __shared__ unsigned short Als[128*32];
  __shared__ unsigned short Bls[128*32];
  int t = threadIdx.x, w = t>>6, lane = t&63;
  int m0 = blockIdx.x*128, n0 = blockIdx.y*128;
  int wm = (w>>1)*64, wn = (w&1)*64;
  int lrow = lane&15, lk = (lane>>4)*8, rg = lane>>4;
  f32x4 acc[4][4] = {};
  for (int k0=0; k0<K; k0+=32){
    #pragma unroll
    for (int i=0;i<2;i++){
      int c = t + i*256;
      gld_lds16(A  + (size_t)(m0 + (c>>2))*K + k0 + (c&3)*8, Als + c*8);
      gld_lds16(Bw + (size_t)(n0 + (c>>2))*K + k0 + (c&3)*8, Bls + c*8);
    }
    __syncthreads();
    bf16x8 a[4], b[4];
    #pragma unroll
    for (int i=0;i<4;i++){
      a[i] = *(const bf16x8*)&Als[(wm + i*16 + lrow)*32 + lk];
      b[i] = *(const bf16x8*)&Bls[(wn + i*16 + lrow)*32 + lk];
    }
    #pragma unroll
    for (int mi=0;mi<4;mi++)
      #pragma unroll
      for (int ni=0;ni<4;ni++)
        acc[mi][ni] = __builtin_amdgcn_mfma_f32_16x16x32_bf16(a[mi], b[ni], acc[mi][ni], 0,0,0);
    __syncthreads();
  }
  #pragma unroll
  for (int mi=0;mi<4;mi++){
    #pragma unroll
    for (int ni=0;ni<4;ni++){
      int n = n0 + wn + ni*16 + lrow;
      float bs = (MODE==2) ? 0.f : bias[n];
      float scl = (MODE==3 && n < FDIM) ? QSCL : 1.0f;
      #pragma unroll
      for (int r=0;r<4;r++){
        int m = m0 + wm + mi*16 + rg*4 + r;
        float vv = acc[mi][ni][r] + ((MODE==2) ? bias[m] : bs);
        if (MODE==3) vv *= scl;
        size_t idx = (size_t)m*Nout + n;
        if (MODE==1) ((float*)Cout)[idx] = vv + resid[idx];
        else         ((unsigned short*)Cout)[idx] = f2bf(vv);
      }
    }
  }
}

// ---------------- Flash attention, swapped-QK^T 32x32 structure ----------------
// Per wave: 32 q-rows, fully independent. No LDS, no barriers.
// S^T = mfma(A=K[32k x 16d], B=Q[16d x 32q]) -> lane holds q=lane&31, 16 keys in regs
//   (key = (r&3) + 8*(r>>2) + 4*hi, hi = lane>>5).
// Softmax fully in-register: in-lane tree + one shfl_xor(32) combine; defer-max THR=8.
// P -> bf16 A-fragment via v_cvt_pk_bf16_f32 + shfl_xor(32) half-exchange.
// O = mfma(A=P[32q x 16k], B=V[16k x 32d]); K/V register double-buffered (prefetch t+1).
// qk: [B*N, 2F] bf16 (Q pre-scaled by 0.125*log2e); vt: [F][B*N] bf16 (V^T).
__global__ __launch_bounds__(256, 2) void attn(const unsigned short* __restrict__ qk,
                                               const unsigned short* __restrict__ vt,
                                               unsigned short* __restrict__ wvbuf){
  int t=threadIdx.x, w=t>>6, lane=t&63;
  int q=lane&31, hi=lane>>5;
  // XCD-chunked decode: 64 consecutive logical wgids per XCD (512 % 8 == 0, bijective)
  int bid = blockIdx.x;
  int wgid = (bid&7)*64 + (bid>>3);
  int qt = wgid&7, h = (wgid>>3)&15, b = wgid>>7;
  int q0 = qt*128 + w*32;
  const size_t qs = 2*FDIM;

  // Q fragments (B-operand): lane holds col q=lane&31, d-slice ks*16 + hi*8
  const unsigned short* qptr = qk + (size_t)(b*SEQ + q0 + q)*qs + h*HDIM + hi*8;
  bf16x8 qf[4];
  #pragma unroll
  for (int ks=0; ks<4; ks++) qf[ks] = *(const bf16x8*)(qptr + ks*16);

  // K (A-operand): lane holds key-row key0 + (lane&31), d-slice ks*16 + hi*8
  const unsigned short* kptr = qk + (size_t)(b*SEQ + q)*qs + FDIM + h*HDIM + hi*8;
  // V (B-operand): lane holds col d = dt*32 + (lane&31), key-slice key0 + kp*16 + hi*8
  const unsigned short* vptr = vt + (size_t)(h*HDIM + q)*MROWS + b*SEQ + hi*8;

  f32x16 o0 = {}, o1 = {};
  float m_run = -1e30f, l_run = 0.f;

  bf16x8 kbA[4], vbA[2][2], kbB[4], vbB[2][2];

  auto loadT = [&](bf16x8 (&kb)[4], bf16x8 (&vb)[2][2], int key0){
    #pragma unroll
    for (int ks=0; ks<4; ks++)
      kb[ks] = *(const bf16x8*)(kptr + (size_t)key0*qs + ks*16);
    #pragma unroll
    for (int dt=0; dt<2; dt++)
      #pragma unroll
      for (int kp=0; kp<2; kp++)
        vb[dt][kp] = *(const bf16x8*)(vptr + (size_t)dt*32*MROWS + key0 + kp*16);
  };

  auto body = [&](bf16x8 (&kb)[4], bf16x8 (&vb)[2][2]){
    // S^T = K . Q^T over d (accumulate 4 k-slices)
    f32x16 s = {};
    #pragma unroll
    for (int ks=0; ks<4; ks++)
      s = __builtin_amdgcn_mfma_f32_32x32x16_bf16(kb[ks], qf[ks], s, 0,0,0);
    // tile max over this lane's 16 keys, combine with partner lane (lane^32)
    float tm = fmaxf(s[0], s[1]);
    #pragma unroll
    for (int r=2;r<16;r++) tm = fmaxf(tm, s[r]);
    tm = fmaxf(tm, __shfl_xor(tm, 32));
    // defer-max: only rescale when some row grew by > 8 (exp2 domain; P <= 256)
    if (!__all(tm <= m_run + 8.0f)){
      float mn = fmaxf(m_run, tm);
      float sc = exp2f(m_run - mn);
      l_run *= sc;
      #pragma unroll
      for (int r=0;r<16;r++){ o0[r]*=sc; o1[r]*=sc; }
      m_run = mn;
    }
    float p[16]; float ts = 0.f;
    #pragma unroll
    for (int r=0;r<16;r++){ p[r] = exp2f(s[r] - m_run); ts += p[r]; }
    ts += __shfl_xor(ts, 32);
    l_run += ts;
    // pack P into PV A-fragments: k = kp*16 + hi*8 + j
    // own regs 8kp+0..7 hold keys kp*16 + {0..3}+4*hi interleaved with 8-offset;
    // lo-lane needs partner w0,w1 (keys +4..7); hi-lane needs partner w2,w3 (keys +8..11)
    bf16x8 pf[2];
    #pragma unroll
    for (int kp=0; kp<2; kp++){
      uint32_t w0 = cvtpk(p[8*kp+0], p[8*kp+1]);
      uint32_t w1 = cvtpk(p[8*kp+2], p[8*kp+3]);
      uint32_t w2 = cvtpk(p[8*kp+4], p[8*kp+5]);
      uint32_t w3 = cvtpk(p[8*kp+6], p[8*kp+7]);
      uint32_t e0 = __shfl_xor(hi ? w0 : w2, 32);
      uint32_t e1 = __shfl_xor(hi ? w1 : w3, 32);
      union { uint32_t u[4]; bf16x8 v; } fr;
      fr.u[0] = hi ? e0 : w0;
      fr.u[1] = hi ? e1 : w1;
      fr.u[2] = hi ? w2 : e0;
      fr.u[3] = hi ? w3 : e1;
      pf[kp] = fr.v;
    }
    // O += P V  (2 d-tiles x 2 k-slots)
    o0 = __builtin_amdgcn_mfma_f32_32x32x16_bf16(pf[0], vb[0][0], o0, 0,0,0);
    o0 = __builtin_amdgcn_mfma_f32_32x32x16_bf16(pf[1], vb[0][1], o0, 0,0,0);
    o1 = __builtin_amdgcn_mfma_f32_32x32x16_bf16(pf[0], vb[1][0], o1, 0,0,0);
    o1 = __builtin_amdgcn_mfma_f32_32x32x16_bf16(pf[1], vb[1][1], o1, 0,0,0);
  };

  loadT(kbA, vbA, 0);
  for (int it=0; it<16; ++it){
    loadT(kbB, vbB, it*64 + 32);     // prefetch odd tile
    body(kbA, vbA);                  // compute even tile
    if (it < 15) loadT(kbA, vbA, it*64 + 64);  // prefetch next even tile
    body(kbB, vbB);                  // compute odd tile
  }

  // epilogue: O row q_row = (r&3)+8*(r>>2)+4*hi, col d = dt*32 + q
  #pragma unroll
  for (int r=0;r<16;r++){
    int qr = (r&3) + 8*(r>>2) + 4*hi;
    float lq = __shfl(l_run, qr);
    float inv = 1.0f / lq;
    size_t base = (size_t)(b*SEQ + q0 + qr)*FDIM + h*HDIM + q;
    wvbuf[base]      = f2bf(o0[r]*inv);
    wvbuf[base + 32] = f2bf(o1[r]*inv);
  }
}

extern "C" void kernel_launch(void* const* d_in, const int* in_sizes, int n_in,
                              void* d_out, int out_size, void* d_ws, size_t ws_size,
                              hipStream_t stream) {
  const float* in_feats = (const float*)d_in[0];
  const float* pos      = (const float*)d_in[1];
  const float* ln_g     = (const float*)d_in[2];
  const float* ln_b     = (const float*)d_in[3];
  const float* w_qk     = (const float*)d_in[4];
  const float* b_qk     = (const float*)d_in[5];
  const float* w_v      = (const float*)d_in[6];
  const float* b_v      = (const float*)d_in[7];
  const float* w_o      = (const float*)d_in[8];
  const float* b_o      = (const float*)d_in[9];
  float* out = (float*)d_out;

  char* ws = (char*)d_ws;
  unsigned short* norm_b = (unsigned short*)(ws + 0);              // 8 MiB
  unsigned short* posn_b = (unsigned short*)(ws + (8u<<20));       // 8 MiB
  unsigned short* wqk_b  = (unsigned short*)(ws + (16u<<20));      // 4 MiB
  unsigned short* wv_b   = (unsigned short*)(ws + (20u<<20));      // 2 MiB
  unsigned short* wo_b   = (unsigned short*)(ws + (22u<<20));      // 2 MiB
  unsigned short* qk_buf = (unsigned short*)(ws + (24u<<20));      // 16 MiB
  unsigned short* vt_buf = (unsigned short*)(ws + (40u<<20));      // 8 MiB  [1024][4096]
  unsigned short* wv_out = norm_b;  // reuse: norm no longer needed once attn runs

  cvt_all<<<4096, 256, 0, stream>>>(w_qk, w_v, w_o, wqk_b, wv_b, wo_b);
  ln_posadd<<<MROWS, 256, 0, stream>>>(in_feats, pos, ln_g, ln_b, norm_b, posn_b);
  // QK projection: [4096,2048] = posn @ w_qk^T ; Q half pre-scaled by 0.125*log2(e)
  gemm_bt<3><<<dim3(MROWS/128, 2048/128), 256, 0, stream>>>(posn_b, wqk_b, b_qk, nullptr,
                                                            qk_buf, MROWS, 2048, FDIM);
  // V^T projection: [1024,4096] = w_v @ norm^T  (bias per output row)
  gemm_bt<2><<<dim3(FDIM/128, MROWS/128), 256, 0, stream>>>(wv_b, norm_b, b_v, nullptr,
                                                            vt_buf, FDIM, MROWS, FDIM);
  attn<<<dim3(512), 256, 0, stream>>>(qk_buf, vt_buf, wv_out);
  // O projection + bias + residual -> fp32 out
  gemm_bt<1><<<dim3(MROWS/128, 1024/128), 256, 0, stream>>>(wv_out, wo_b, b_o, in_feats,
                                                            out, MROWS, 1024, FDIM);
}